// Round 13
// baseline (1110.174 us; speedup 1.0000x reference)
//
#include <hip/hip_runtime.h>
#include <hip/hip_bf16.h>
#include <math.h>

#define IN_CH  256
#define MID    512
#define MID2   256
#define OUT_CH 64

typedef __attribute__((ext_vector_type(8))) short s16x8;
typedef __attribute__((ext_vector_type(8))) unsigned short u16x8;
typedef __attribute__((ext_vector_type(4))) float f32x4;

// ---------------- CSR build ----------------

__global__ __launch_bounds__(256) void deg_kernel(const int* __restrict__ dst,
                                                  int* __restrict__ cnt, int E) {
  int stride = gridDim.x * blockDim.x;
  for (int e = blockIdx.x * blockDim.x + threadIdx.x; e < E; e += stride)
    atomicAdd(&cnt[dst[e]], 1);
}

__global__ __launch_bounds__(1024) void scan_dis_kernel(const int* __restrict__ cnt,
                                                        int* __restrict__ rowstart,
                                                        float* __restrict__ dis, int N) {
  __shared__ int part[1024];
  int t = threadIdx.x;
  int chunk = (N + 1023) >> 10;
  int lo = t * chunk;
  int hi = lo + chunk; if (hi > N) hi = N; if (lo > N) lo = N;
  int s = 0;
  for (int i = lo; i < hi; ++i) s += cnt[i] + 1;
  part[t] = s;
  __syncthreads();
  for (int off = 1; off < 1024; off <<= 1) {
    int v = (t >= off) ? part[t - off] : 0;
    __syncthreads();
    part[t] += v;
    __syncthreads();
  }
  int base = part[t] - s;  // exclusive prefix
  for (int i = lo; i < hi; ++i) {
    int d = cnt[i] + 1;
    rowstart[i] = base;
    dis[i] = rsqrtf((float)d);
    base += d;
  }
  if (t == 1023) rowstart[N] = part[1023];
}

__global__ __launch_bounds__(256) void fill_adj_kernel(const int* __restrict__ src,
                                                       const int* __restrict__ dst,
                                                       const int* __restrict__ rowstart,
                                                       int* __restrict__ cnt2,
                                                       int* __restrict__ adj,
                                                       int E, int N) {
  int total = E + N;
  int stride = gridDim.x * blockDim.x;
  for (int e = blockIdx.x * blockDim.x + threadIdx.x; e < total; e += stride) {
    int s, d;
    if (e < E) { s = src[e]; d = dst[e]; }
    else       { s = d = e - E; }                 // self-loop
    int pos = rowstart[d] + atomicAdd(&cnt2[d], 1);
    adj[pos] = s;
  }
}

// ---------------- bf16 split helpers ----------------

__device__ inline unsigned bf16_rne(float v) {
  unsigned u = __float_as_uint(v);
  return (u + 0x7FFFu + ((u >> 16) & 1u)) >> 16;
}

// W[K][F] fp32 -> Th/Tl rows [noff+n][k] bf16 bits (row stride K)
__global__ __launch_bounds__(256) void wsplit_cat(const float* __restrict__ W,
                                                  unsigned short* __restrict__ Th,
                                                  unsigned short* __restrict__ Tl,
                                                  int K, int F, int noff) {
  int idx = blockIdx.x * 256 + threadIdx.x;
  if (idx >= K * F) return;
  int k = idx / F, n = idx - k * F;
  float v = W[idx];
  unsigned h = bf16_rne(v);
  float hf = __uint_as_float(h << 16);
  unsigned l = bf16_rne(v - hf);
  Th[(size_t)(noff + n) * K + k] = (unsigned short)h;
  Tl[(size_t)(noff + n) * K + k] = (unsigned short)l;
}

// X fp32 -> Xh/Xl bf16 pair, elementwise (8 elems/thread)
__global__ __launch_bounds__(256) void split_pair(const float* __restrict__ X,
                                                  unsigned short* __restrict__ Xh,
                                                  unsigned short* __restrict__ Xl,
                                                  int n8) {
  int i = blockIdx.x * 256 + threadIdx.x;
  if (i >= n8) return;
  const float4* xp = (const float4*)X + (size_t)i * 2;
  float4 a = xp[0], b = xp[1];
  float vv[8] = {a.x, a.y, a.z, a.w, b.x, b.y, b.z, b.w};
  u16x8 hv, lv;
  #pragma unroll
  for (int j = 0; j < 8; ++j) {
    unsigned h = bf16_rne(vv[j]);
    float hf = __uint_as_float(h << 16);
    unsigned l = bf16_rne(vv[j] - hf);
    hv[j] = (unsigned short)h;
    lv[j] = (unsigned short)l;
  }
  ((u16x8*)Xh)[i] = hv;
  ((u16x8*)Xl)[i] = lv;
}

// ---------------- barrier-free direct-from-global MFMA GEMM (3-pass bf16 split) ----
// One 64-lane wave per 64x64 output tile. No LDS, no __syncthreads.
// A as Agh/Agl [Nrows][KK] bf16 pairs; B as Bgh/Bgl [Fcols][KK] (transposed).
// Fragments load 16B/lane direct from global: one load instr = 16 rows x 64B
// (full cache lines). A and B share the (lane,elem)->k map: k = k0 + (lane>>4)*8 + j
// -- identical to the previous LDS-swizzled kernel's mapping (bit-identical math).
// KK is compile-time so the K loop fully unrolls -> compiler software-pipelines
// loads across MFMAs with no barrier drain (the round-9 latency fix).
// MODE 0: C1w[rr*F1+cc] = v + bias[cc]                        (all cols)
// MODE 1: t = C1r[] + elu(v + bias[cc]); O2h/O2l[] = split(t) (all cols)
// MODE 2: cc<F1: C1w = v+bias; else O2h[cc-F1] = bf16(v)      (dual)
// MODE 3: cc<F1: C1w = v+bias; else O2f[cc-F1] = v            (dual)

template<int MODE, int KK>
__global__ __launch_bounds__(64, 2)
void gemm_dw(const unsigned short* __restrict__ Agh, const unsigned short* __restrict__ Agl,
             const unsigned short* __restrict__ Bgh, const unsigned short* __restrict__ Bgl,
             const float* __restrict__ bias,
             const float* __restrict__ C1r, float* __restrict__ C1w,
             unsigned short* __restrict__ O2h, unsigned short* __restrict__ O2l,
             float* __restrict__ O2f,
             int Nrows, int F1) {
  const int lane = threadIdx.x;          // 64 lanes
  const int row0 = blockIdx.x * 64;
  const int col0 = blockIdx.y * 64;
  const int l15  = lane & 15;
  const int kgrp = (lane >> 4) << 3;     // 0,8,16,24 within a 32-wide k slice

  f32x4 acc[4][4] = {};

  size_t aoff[4], boff[4];
  #pragma unroll
  for (int mi = 0; mi < 4; ++mi) {
    int r = row0 + mi * 16 + l15;
    if (r > Nrows - 1) r = Nrows - 1;    // clamp OOB rows (epilogue skips them)
    aoff[mi] = (size_t)r * KK + kgrp;
  }
  #pragma unroll
  for (int ni = 0; ni < 4; ++ni)
    boff[ni] = (size_t)(col0 + ni * 16 + l15) * KK + kgrp;

  #pragma unroll
  for (int k0 = 0; k0 < KK; k0 += 32) {
    s16x8 fah[4], fal[4], fbh[4], fbl[4];
    #pragma unroll
    for (int mi = 0; mi < 4; ++mi) {
      fah[mi] = *(const s16x8*)(Agh + aoff[mi] + k0);
      fal[mi] = *(const s16x8*)(Agl + aoff[mi] + k0);
    }
    #pragma unroll
    for (int ni = 0; ni < 4; ++ni) {
      fbh[ni] = *(const s16x8*)(Bgh + boff[ni] + k0);
      fbl[ni] = *(const s16x8*)(Bgl + boff[ni] + k0);
    }
    #pragma unroll
    for (int mi = 0; mi < 4; ++mi)
      #pragma unroll
      for (int ni = 0; ni < 4; ++ni) {
        acc[mi][ni] = __builtin_amdgcn_mfma_f32_16x16x32_bf16(fah[mi], fbh[ni], acc[mi][ni], 0, 0, 0);
        acc[mi][ni] = __builtin_amdgcn_mfma_f32_16x16x32_bf16(fah[mi], fbl[ni], acc[mi][ni], 0, 0, 0);
        acc[mi][ni] = __builtin_amdgcn_mfma_f32_16x16x32_bf16(fal[mi], fbh[ni], acc[mi][ni], 0, 0, 0);
      }
  }

  // epilogue: C/D mapping col=lane&15, row=(lane>>4)*4+reg   [m89-verified]
  #pragma unroll
  for (int mi = 0; mi < 4; ++mi) {
    #pragma unroll
    for (int r = 0; r < 4; ++r) {
      int rr = row0 + mi * 16 + (lane >> 4) * 4 + r;
      if (rr >= Nrows) continue;
      #pragma unroll
      for (int ni = 0; ni < 4; ++ni) {
        int cc = col0 + ni * 16 + l15;
        float v = acc[mi][ni][r];
        if (MODE == 0) {
          C1w[(size_t)rr * F1 + cc] = v + bias[cc];
        } else if (MODE == 1) {
          float t = v + bias[cc];
          t = (t > 0.f) ? t : expm1f(t);
          t += C1r[(size_t)rr * F1 + cc];
          size_t idx = (size_t)rr * F1 + cc;
          unsigned h = bf16_rne(t);
          float hf = __uint_as_float(h << 16);
          unsigned l = bf16_rne(t - hf);
          O2h[idx] = (unsigned short)h;
          O2l[idx] = (unsigned short)l;
        } else {
          if (cc < F1) {
            C1w[(size_t)rr * F1 + cc] = v + bias[cc];
          } else {
            size_t idx = (size_t)rr * F1 + (cc - F1);
            if (MODE == 2) O2h[idx] = (unsigned short)bf16_rne(v);
            else           O2f[idx] = v;
          }
        }
      }
    }
  }
}

// ---------------- aggregation kernels (one wave per node) ----------------

// z = dis[i] * sum_s H[s]*dis[s]  -> split bf16 pair (no bias/elu/add)
template<int F>
__global__ __launch_bounds__(256) void agg_split(const unsigned short* __restrict__ H,
                                                 const int* __restrict__ adj,
                                                 const int* __restrict__ rowstart,
                                                 const float* __restrict__ dis,
                                                 unsigned short* __restrict__ Zh,
                                                 unsigned short* __restrict__ Zl, int N) {
  constexpr int VF = F / 64;  // 4 for F=256
  typedef __attribute__((ext_vector_type(VF))) unsigned short uvec;
  int node = (int)((blockIdx.x * blockDim.x + threadIdx.x) >> 6);
  int lane = threadIdx.x & 63;
  if (node >= N) return;
  int e = rowstart[node];
  const int end = rowstart[node + 1];

  float acc[VF] = {};
  const unsigned short* base = H + (size_t)lane * VF;
  for (; e + 4 <= end; e += 4) {
    int s0 = adj[e], s1 = adj[e + 1], s2 = adj[e + 2], s3 = adj[e + 3];
    float w0 = dis[s0], w1 = dis[s1], w2 = dis[s2], w3 = dis[s3];
    uvec v0 = *(const uvec*)(base + (size_t)s0 * F);
    uvec v1 = *(const uvec*)(base + (size_t)s1 * F);
    uvec v2 = *(const uvec*)(base + (size_t)s2 * F);
    uvec v3 = *(const uvec*)(base + (size_t)s3 * F);
    #pragma unroll
    for (int j = 0; j < VF; ++j) {
      acc[j] = fmaf(__uint_as_float((unsigned)v0[j] << 16), w0, acc[j]);
      acc[j] = fmaf(__uint_as_float((unsigned)v1[j] << 16), w1, acc[j]);
      acc[j] = fmaf(__uint_as_float((unsigned)v2[j] << 16), w2, acc[j]);
      acc[j] = fmaf(__uint_as_float((unsigned)v3[j] << 16), w3, acc[j]);
    }
  }
  for (; e < end; ++e) {
    int s = adj[e]; float w = dis[s];
    uvec v = *(const uvec*)(base + (size_t)s * F);
    #pragma unroll
    for (int j = 0; j < VF; ++j)
      acc[j] = fmaf(__uint_as_float((unsigned)v[j] << 16), w, acc[j]);
  }

  float di = dis[node];
  uvec hv, lv;
  #pragma unroll
  for (int j = 0; j < VF; ++j) {
    float val = acc[j] * di;
    unsigned h = bf16_rne(val);
    float hf = __uint_as_float(h << 16);
    unsigned l = bf16_rne(val - hf);
    hv[j] = (unsigned short)h;
    lv[j] = (unsigned short)l;
  }
  *(uvec*)(Zh + (size_t)node * F + lane * VF) = hv;
  *(uvec*)(Zl + (size_t)node * F + lane * VF) = lv;
}

// t = elu(dis[i]*sum + bias) + lin[i]  -> split bf16 pair (layer-2 output h2)
template<int F>
__global__ __launch_bounds__(256) void agg_addsplit(const unsigned short* __restrict__ H,
                                                    const int* __restrict__ adj,
                                                    const int* __restrict__ rowstart,
                                                    const float* __restrict__ dis,
                                                    const float* __restrict__ bias,
                                                    const float* __restrict__ lin,
                                                    unsigned short* __restrict__ Zh,
                                                    unsigned short* __restrict__ Zl, int N) {
  constexpr int VF = F / 64;
  typedef __attribute__((ext_vector_type(VF))) unsigned short uvec;
  int node = (int)((blockIdx.x * blockDim.x + threadIdx.x) >> 6);
  int lane = threadIdx.x & 63;
  if (node >= N) return;
  int e = rowstart[node];
  const int end = rowstart[node + 1];

  float acc[VF] = {};
  const unsigned short* base = H + (size_t)lane * VF;
  for (; e + 4 <= end; e += 4) {
    int s0 = adj[e], s1 = adj[e + 1], s2 = adj[e + 2], s3 = adj[e + 3];
    float w0 = dis[s0], w1 = dis[s1], w2 = dis[s2], w3 = dis[s3];
    uvec v0 = *(const uvec*)(base + (size_t)s0 * F);
    uvec v1 = *(const uvec*)(base + (size_t)s1 * F);
    uvec v2 = *(const uvec*)(base + (size_t)s2 * F);
    uvec v3 = *(const uvec*)(base + (size_t)s3 * F);
    #pragma unroll
    for (int j = 0; j < VF; ++j) {
      acc[j] = fmaf(__uint_as_float((unsigned)v0[j] << 16), w0, acc[j]);
      acc[j] = fmaf(__uint_as_float((unsigned)v1[j] << 16), w1, acc[j]);
      acc[j] = fmaf(__uint_as_float((unsigned)v2[j] << 16), w2, acc[j]);
      acc[j] = fmaf(__uint_as_float((unsigned)v3[j] << 16), w3, acc[j]);
    }
  }
  for (; e < end; ++e) {
    int s = adj[e]; float w = dis[s];
    uvec v = *(const uvec*)(base + (size_t)s * F);
    #pragma unroll
    for (int j = 0; j < VF; ++j)
      acc[j] = fmaf(__uint_as_float((unsigned)v[j] << 16), w, acc[j]);
  }

  float di = dis[node];
  const float* bp = bias + lane * VF;
  const float* lp = lin + (size_t)node * F + lane * VF;
  uvec hv, lv;
  #pragma unroll
  for (int j = 0; j < VF; ++j) {
    float val = fmaf(acc[j], di, bp[j]);
    val = (val > 0.f) ? val : expm1f(val);
    val += lp[j];
    unsigned h = bf16_rne(val);
    float hf = __uint_as_float(h << 16);
    unsigned l = bf16_rne(val - hf);
    hv[j] = (unsigned short)h;
    lv[j] = (unsigned short)l;
  }
  *(uvec*)(Zh + (size_t)node * F + lane * VF) = hv;
  *(uvec*)(Zl + (size_t)node * F + lane * VF) = lv;
}

// fp32 gather, layer-3 F=64: out += dis[i]*sum + bias
template<int F>
__global__ __launch_bounds__(256) void agg_f32(const float* __restrict__ H,
                                               const int* __restrict__ adj,
                                               const int* __restrict__ rowstart,
                                               const float* __restrict__ dis,
                                               const float* __restrict__ bias,
                                               float* __restrict__ out, int N) {
  int node = (int)((blockIdx.x * blockDim.x + threadIdx.x) >> 6);
  int lane = threadIdx.x & 63;
  if (node >= N) return;
  int e = rowstart[node];
  const int end = rowstart[node + 1];
  float acc = 0.f;
  for (; e + 4 <= end; e += 4) {
    int s0 = adj[e], s1 = adj[e + 1], s2 = adj[e + 2], s3 = adj[e + 3];
    float w0 = dis[s0], w1 = dis[s1], w2 = dis[s2], w3 = dis[s3];
    float q0 = H[(size_t)s0 * F + lane], q1 = H[(size_t)s1 * F + lane];
    float q2 = H[(size_t)s2 * F + lane], q3 = H[(size_t)s3 * F + lane];
    acc = fmaf(q0, w0, acc); acc = fmaf(q1, w1, acc);
    acc = fmaf(q2, w2, acc); acc = fmaf(q3, w3, acc);
  }
  for (; e < end; ++e) {
    int s = adj[e];
    acc = fmaf(H[(size_t)s * F + lane], dis[s], acc);
  }
  out[(size_t)node * F + lane] += fmaf(acc, dis[node], bias[lane]);
}

// ---------------- launch ----------------

static inline char* ws_align(char*& ws, size_t bytes) {
  ws = (char*)(((uintptr_t)ws + 255) & ~(uintptr_t)255);
  char* p = ws;
  ws += bytes;
  return p;
}

extern "C" void kernel_launch(void* const* d_in, const int* in_sizes, int n_in,
                              void* d_out, int out_size, void* d_ws, size_t ws_size,
                              hipStream_t stream) {
  const float* x   = (const float*)d_in[0];
  const int*  eidx = (const int*)d_in[1];
  const float* Wg1 = (const float*)d_in[2];
  const float* bg1 = (const float*)d_in[3];
  const float* Wg2 = (const float*)d_in[4];
  const float* bg2 = (const float*)d_in[5];
  const float* Wg3 = (const float*)d_in[6];
  const float* bg3 = (const float*)d_in[7];
  const float* Wl1 = (const float*)d_in[8];
  const float* bl1 = (const float*)d_in[9];
  const float* Wl2 = (const float*)d_in[10];
  const float* bl2 = (const float*)d_in[11];
  const float* Wl3 = (const float*)d_in[12];
  const float* bl3 = (const float*)d_in[13];

  const int N = in_sizes[0] / IN_CH;
  const int E = in_sizes[1] / 2;
  const int* esrc = eidx;
  const int* edst = eidx + E;

  // ---- workspace layout (explicit lifetime-based aliasing) ----
  char* ws = (char*)d_ws;
  // S1: x split pair (live: split_x .. gemm0)  -> then reused as h1h (gemm1 output)
  unsigned short* xh = (unsigned short*)ws_align(ws, (size_t)N * IN_CH * 2);
  unsigned short* xl = (unsigned short*)ws_align(ws, (size_t)N * IN_CH * 2);
  unsigned short* h1h = xh;  // 51.2 MB contiguous (xh+xl), written by gemm1 AFTER gemm0 read x
  // S2: z split pair (live: agg_split .. gemm1) -> then reused as h2lin (gemm2 output)
  unsigned short* zh = (unsigned short*)ws_align(ws, (size_t)N * IN_CH * 2);
  unsigned short* zl = (unsigned short*)ws_align(ws, (size_t)N * IN_CH * 2);
  float* h2lin = (float*)zh;  // 51.2 MB, written by gemm2 AFTER gemm1 read z
  // S3: h1lin fp32 (live: gemm0 .. gemm1) -> then carved into Hbf / h2h / h2l / Hb3
  float* h1lin = (float*)ws_align(ws, (size_t)N * MID * 4);
  unsigned short* Hbf = (unsigned short*)h1lin;                       // N*256*2
  unsigned short* h2h = (unsigned short*)((char*)h1lin + (size_t)N * MID2 * 2);
  unsigned short* h2l = (unsigned short*)((char*)h1lin + (size_t)N * MID2 * 4);
  float*          Hb3 = (float*)((char*)h1lin + (size_t)N * MID2 * 6);  // N*64*4
  // S4: h1l (live: gemm1 .. gemm2)
  unsigned short* h1l = (unsigned short*)ws_align(ws, (size_t)N * MID * 2);
  // persistent small stuff
  float* dis      = (float*)ws_align(ws, (size_t)N * 4);
  int*   rowstart = (int*)ws_align(ws, (size_t)(N + 1) * 4);
  int*   cnt      = (int*)ws_align(ws, (size_t)N * 4);
  int*   cnt2     = (int*)ws_align(ws, (size_t)N * 4);
  int*   adj      = (int*)ws_align(ws, (size_t)(E + N) * 4);
  // pre-split transposed weights: w1 [1024][256] (Wl1 rows 0..511, Wg1 rows 512..1023),
  // w2 [512][512] (Wl2|Wg2), w3 [128][256] (Wl3|Wg3)
  unsigned short* w1h = (unsigned short*)ws_align(ws, (size_t)1024 * IN_CH * 2);
  unsigned short* w1l = (unsigned short*)ws_align(ws, (size_t)1024 * IN_CH * 2);
  unsigned short* w2h = (unsigned short*)ws_align(ws, (size_t)512 * MID * 2);
  unsigned short* w2l = (unsigned short*)ws_align(ws, (size_t)512 * MID * 2);
  unsigned short* w3h = (unsigned short*)ws_align(ws, (size_t)128 * MID2 * 2);
  unsigned short* w3l = (unsigned short*)ws_align(ws, (size_t)128 * MID2 * 2);

  // ---- CSR build ----
  hipMemsetAsync(cnt, 0, (size_t)N * 4, stream);
  hipMemsetAsync(cnt2, 0, (size_t)N * 4, stream);
  deg_kernel<<<1024, 256, 0, stream>>>(edst, cnt, E);
  scan_dis_kernel<<<1, 1024, 0, stream>>>(cnt, rowstart, dis, N);
  fill_adj_kernel<<<2048, 256, 0, stream>>>(esrc, edst, rowstart, cnt2, adj, E, N);

  // ---- weight split (tiny) ----
  {
    int n1 = IN_CH * MID, n2 = MID * MID2, n3 = MID2 * OUT_CH;
    wsplit_cat<<<(n1 + 255) / 256, 256, 0, stream>>>(Wl1, w1h, w1l, IN_CH, MID, 0);
    wsplit_cat<<<(n1 + 255) / 256, 256, 0, stream>>>(Wg1, w1h, w1l, IN_CH, MID, MID);
    wsplit_cat<<<(n2 + 255) / 256, 256, 0, stream>>>(Wl2, w2h, w2l, MID, MID2, 0);
    wsplit_cat<<<(n2 + 255) / 256, 256, 0, stream>>>(Wg2, w2h, w2l, MID, MID2, MID2);
    wsplit_cat<<<(n3 + 255) / 256, 256, 0, stream>>>(Wl3, w3h, w3l, MID2, OUT_CH, 0);
    wsplit_cat<<<(n3 + 255) / 256, 256, 0, stream>>>(Wg3, w3h, w3l, MID2, OUT_CH, OUT_CH);
  }

  // ---- x -> bf16 split pair ----
  {
    int n8 = N * IN_CH / 8;
    split_pair<<<(n8 + 255) / 256, 256, 0, stream>>>(x, xh, xl, n8);
  }

  const int aggBlocks = (N + 3) / 4;
  const int rb64 = (N + 63) / 64;   // 64-row tiles for the wave GEMM
  float* outp = (float*)d_out;

  // ---- layer 1 ----
  // z = agg(x) in input space (256-dim, bf16 gather on xh)
  agg_split<IN_CH><<<aggBlocks, 256, 0, stream>>>(xh, adj, rowstart, dis, zh, zl, N);
  // h1lin = x @ Wl1 + bl1
  dim3 g1(rb64, MID / 64);
  gemm_dw<0, IN_CH><<<g1, 64, 0, stream>>>(xh, xl, w1h, w1l, bl1,
                                           nullptr, h1lin, nullptr, nullptr, nullptr,
                                           N, MID);
  // h1 = elu(z @ Wg1 + bg1) + h1lin  -> split pair (h1h over S1, h1l fresh)
  gemm_dw<1, IN_CH><<<g1, 64, 0, stream>>>(zh, zl,
                                           w1h + (size_t)MID * IN_CH, w1l + (size_t)MID * IN_CH, bg1,
                                           h1lin, nullptr, h1h, h1l, nullptr,
                                           N, MID);

  // ---- layer 2 ----
  // dual: h2lin = h1 @ Wl2 + bl2 ; Hbf = bf16(h1 @ Wg2)
  dim3 g2(rb64, (2 * MID2) / 64);
  gemm_dw<2, MID><<<g2, 64, 0, stream>>>(h1h, h1l, w2h, w2l, bl2,
                                         nullptr, h2lin, Hbf, nullptr, nullptr,
                                         N, MID2);
  // h2 = elu(agg(Hbf)+bg2) + h2lin -> split pair
  agg_addsplit<MID2><<<aggBlocks, 256, 0, stream>>>(Hbf, adj, rowstart, dis, bg2, h2lin, h2h, h2l, N);

  // ---- layer 3 ----
  // dual: out = h2 @ Wl3 + bl3 ; Hb3 = fp32(h2 @ Wg3)
  dim3 g3(rb64, (2 * OUT_CH) / 64);
  gemm_dw<3, MID2><<<g3, 64, 0, stream>>>(h2h, h2l, w3h, w3l, bl3,
                                          nullptr, outp, nullptr, nullptr, Hb3,
                                          N, OUT_CH);
  // out += agg(Hb3) + bg3
  agg_f32<OUT_CH><<<aggBlocks, 256, 0, stream>>>(Hb3, adj, rowstart, dis, bg3, outp, N);
}